// Round 2
// baseline (1038.427 us; speedup 1.0000x reference)
//
#include <hip/hip_runtime.h>
#include <hip/hip_bf16.h>

#define N_NODES 100000
#define N_EDGES 800000
#define ETOT    900000   // N_EDGES + N_NODES self-loops
#define NGRAPH  256

// ---------------------------------------------------------------- CSR build
__global__ void hist_kernel(const int* __restrict__ ei, int* __restrict__ cnts) {
    int e = blockIdx.x * blockDim.x + threadIdx.x;
    if (e >= ETOT) return;
    int dst = (e < N_EDGES) ? ei[N_EDGES + e] : (e - N_EDGES);
    atomicAdd(&cnts[dst], 1);
}

__global__ void scan1_kernel(const int* __restrict__ cnts, int* __restrict__ row_ptr,
                             int* __restrict__ bsum, int n) {
    __shared__ int sdata[256];
    int tid = threadIdx.x;
    int base = blockIdx.x * 1024 + tid * 4;
    int v0 = (base + 0 < n) ? cnts[base + 0] : 0;
    int v1 = (base + 1 < n) ? cnts[base + 1] : 0;
    int v2 = (base + 2 < n) ? cnts[base + 2] : 0;
    int v3 = (base + 3 < n) ? cnts[base + 3] : 0;
    int ts = v0 + v1 + v2 + v3;
    sdata[tid] = ts;
    __syncthreads();
    for (int off = 1; off < 256; off <<= 1) {
        int t = (tid >= off) ? sdata[tid - off] : 0;
        __syncthreads();
        sdata[tid] += t;
        __syncthreads();
    }
    int run = sdata[tid] - ts;   // exclusive prefix for this thread
    if (base + 0 < n) row_ptr[base + 0] = run; run += v0;
    if (base + 1 < n) row_ptr[base + 1] = run; run += v1;
    if (base + 2 < n) row_ptr[base + 2] = run; run += v2;
    if (base + 3 < n) row_ptr[base + 3] = run;
    if (tid == 255) bsum[blockIdx.x] = sdata[255];
}

__global__ void scan2_kernel(int* __restrict__ bsum, int nb) {
    __shared__ int s[128];
    int tid = threadIdx.x;
    int v = (tid < nb) ? bsum[tid] : 0;
    s[tid] = v;
    __syncthreads();
    for (int off = 1; off < 128; off <<= 1) {
        int t = (tid >= off) ? s[tid - off] : 0;
        __syncthreads();
        s[tid] += t;
        __syncthreads();
    }
    if (tid < nb) bsum[tid] = s[tid] - v;   // exclusive
}

__global__ void scan3_kernel(int* __restrict__ row_ptr, const int* __restrict__ bsum, int n) {
    int i = blockIdx.x * blockDim.x + threadIdx.x;
    if (i < n) row_ptr[i] += bsum[i >> 10];
    if (i == 0) row_ptr[n] = ETOT;
}

__global__ void scatter_kernel(const int* __restrict__ ei, const int* __restrict__ row_ptr,
                               int* __restrict__ fill, int* __restrict__ col_src) {
    int e = blockIdx.x * blockDim.x + threadIdx.x;
    if (e >= ETOT) return;
    int src, dst;
    if (e < N_EDGES) { src = ei[e]; dst = ei[N_EDGES + e]; }
    else             { src = dst = e - N_EDGES; }
    int pos = atomicAdd(&fill[dst], 1);
    col_src[row_ptr[dst] + pos] = src;
}

// ---------------------------------------------------------------- GEMM  hp = h @ W^T
// block: 128 threads; tile 64 nodes x 128 outputs; thread tile 8 nodes x 8 outputs
template<int IN>
__global__ __launch_bounds__(128)
void gemm_kernel(const float* __restrict__ H, const float* __restrict__ W,
                 float* __restrict__ hp, int n_nodes) {
    __shared__ float sH[32][64 + 4];    // [kk][node]
    __shared__ float sW[32][128 + 4];   // [kk][out]
    int tid = threadIdx.x;
    int n0  = blockIdx.x * 64;
    int tx  = tid & 15;        // output group 0..15
    int ty  = tid >> 4;        // node group 0..7
    int o0  = tx * 8;
    int nn0 = ty * 8;
    float acc[8][8];
#pragma unroll
    for (int i = 0; i < 8; ++i)
#pragma unroll
        for (int j = 0; j < 8; ++j) acc[i][j] = 0.f;

    for (int k0 = 0; k0 < IN; k0 += 32) {
        // stage W chunk: 128 out x 32 k
#pragma unroll
        for (int i = 0; i < 8; ++i) {
            int idx = i * 128 + tid;         // 0..1023 float4 units
            int o   = idx >> 3;
            int k4  = (idx & 7) * 4;
            float4 w = *reinterpret_cast<const float4*>(W + (size_t)o * IN + k0 + k4);
            sW[k4 + 0][o] = w.x; sW[k4 + 1][o] = w.y;
            sW[k4 + 2][o] = w.z; sW[k4 + 3][o] = w.w;
        }
        // stage H chunk: 64 nodes x 32 k
#pragma unroll
        for (int i = 0; i < 4; ++i) {
            int idx = i * 128 + tid;         // 0..511 float4 units
            int nn  = idx >> 3;
            int k4  = (idx & 7) * 4;
            int nidx = n0 + nn;
            float4 h = make_float4(0.f, 0.f, 0.f, 0.f);
            if (nidx < n_nodes)
                h = *reinterpret_cast<const float4*>(H + (size_t)nidx * IN + k0 + k4);
            sH[k4 + 0][nn] = h.x; sH[k4 + 1][nn] = h.y;
            sH[k4 + 2][nn] = h.z; sH[k4 + 3][nn] = h.w;
        }
        __syncthreads();
#pragma unroll 8
        for (int kk = 0; kk < 32; ++kk) {
            float4 ha = *reinterpret_cast<float4*>(&sH[kk][nn0]);
            float4 hb = *reinterpret_cast<float4*>(&sH[kk][nn0 + 4]);
            float4 wa = *reinterpret_cast<float4*>(&sW[kk][o0]);
            float4 wb = *reinterpret_cast<float4*>(&sW[kk][o0 + 4]);
            float hv[8] = {ha.x, ha.y, ha.z, ha.w, hb.x, hb.y, hb.z, hb.w};
            float wv[8] = {wa.x, wa.y, wa.z, wa.w, wb.x, wb.y, wb.z, wb.w};
#pragma unroll
            for (int i = 0; i < 8; ++i)
#pragma unroll
                for (int j = 0; j < 8; ++j) acc[i][j] += hv[i] * wv[j];
        }
        __syncthreads();
    }
#pragma unroll
    for (int i = 0; i < 8; ++i) {
        int nn = n0 + nn0 + i;
        if (nn < n_nodes) {
            float4 r0 = make_float4(acc[i][0], acc[i][1], acc[i][2], acc[i][3]);
            float4 r1 = make_float4(acc[i][4], acc[i][5], acc[i][6], acc[i][7]);
            *reinterpret_cast<float4*>(hp + (size_t)nn * 128 + o0)     = r0;
            *reinterpret_cast<float4*>(hp + (size_t)nn * 128 + o0 + 4) = r1;
        }
    }
}

// ---------------------------------------------------------------- attention logits per node
__global__ void al_kernel(const float* __restrict__ hp, const float* __restrict__ a_src,
                          const float* __restrict__ a_dst, float* __restrict__ al_s,
                          float* __restrict__ al_d, int n_nodes) {
    int gid = blockIdx.x * blockDim.x + threadIdx.x;   // one per (node, head)
    int n = gid >> 2, h = gid & 3;
    if (n >= n_nodes) return;
    const float4* hp4 = reinterpret_cast<const float4*>(hp + (size_t)n * 128 + h * 32);
    const float4* as4 = reinterpret_cast<const float4*>(a_src + h * 32);
    const float4* ad4 = reinterpret_cast<const float4*>(a_dst + h * 32);
    float ss = 0.f, sd = 0.f;
#pragma unroll
    for (int i = 0; i < 8; ++i) {
        float4 v = hp4[i], a = as4[i], d = ad4[i];
        ss += v.x * a.x + v.y * a.y + v.z * a.z + v.w * a.w;
        sd += v.x * d.x + v.y * d.y + v.z * d.z + v.w * d.w;
    }
    al_s[gid] = ss;
    al_d[gid] = sd;
}

// ---------------------------------------------------------------- edge aggregation (one wave per dst)
__global__ void aggregate_kernel(const float* __restrict__ hp,
                                 const float* __restrict__ al_s,
                                 const float* __restrict__ al_d,
                                 const int* __restrict__ row_ptr,
                                 const int* __restrict__ col_src,
                                 const float* __restrict__ bias,
                                 float* __restrict__ out,
                                 int n_nodes, int do_relu) {
    int wv   = (blockIdx.x * blockDim.x + threadIdx.x) >> 6;
    int lane = threadIdx.x & 63;
    if (wv >= n_nodes) return;
    int d    = wv;
    int head = lane >> 4;                       // lanes 0-15 head0 ... 48-63 head3
    float ald = al_d[d * 4 + head];
    int beg = row_ptr[d], end = row_ptr[d + 1];
    float m = -INFINITY, s = 0.f, acc0 = 0.f, acc1 = 0.f;
    for (int j = beg; j < end; ++j) {
        int src = col_src[j];
        float e = al_s[src * 4 + head] + ald;
        e = (e > 0.f) ? e : 0.2f * e;           // leaky_relu 0.2
        float nm    = fmaxf(m, e);
        float scale = __expf(m - nm);           // first iter: exp(-inf)=0
        float p     = __expf(e - nm);
        s = s * scale + p;
        float2 v = reinterpret_cast<const float2*>(hp + (size_t)src * 128)[lane];
        acc0 = acc0 * scale + p * v.x;
        acc1 = acc1 * scale + p * v.y;
        m = nm;
    }
    float inv = 1.f / (s + 1e-16f);
    int c0 = lane * 2;
    float o0 = acc0 * inv + bias[c0];
    float o1 = acc1 * inv + bias[c0 + 1];
    if (do_relu) { o0 = fmaxf(o0, 0.f); o1 = fmaxf(o1, 0.f); }
    reinterpret_cast<float2*>(out + (size_t)d * 128)[lane] = make_float2(o0, o1);
}

// ---------------------------------------------------------------- pooling
__global__ void pool_kernel(const float* __restrict__ feat, const int* __restrict__ batch,
                            float* __restrict__ sums, int n) {
    int c = threadIdx.x;                       // 128 channels
    int start = blockIdx.x * 512;
    int end   = min(start + 512, n);
    if (start >= end) return;
    int cur = -1;
    float acc = 0.f;
    for (int nn = start; nn < end; ++nn) {
        int g = batch[nn];                     // sorted -> rare flushes
        if (g != cur) {
            if (cur >= 0) atomicAdd(&sums[cur * 128 + c], acc);
            acc = 0.f; cur = g;
        }
        acc += feat[(size_t)nn * 128 + c];
    }
    if (cur >= 0) atomicAdd(&sums[cur * 128 + c], acc);
}

__global__ void cnt_kernel(const int* __restrict__ batch, int* __restrict__ cntg, int n) {
    int i = blockIdx.x * blockDim.x + threadIdx.x;
    if (i < n) atomicAdd(&cntg[batch[i]], 1);
}

__global__ void div_kernel(const float* __restrict__ sums, const int* __restrict__ cntg,
                           float* __restrict__ out) {
    int i = blockIdx.x * blockDim.x + threadIdx.x;
    if (i < NGRAPH * 128) {
        float c = (float)max(cntg[i >> 7], 1);
        out[i] = sums[i] / c;
    }
}

// ---------------------------------------------------------------- launch
extern "C" void kernel_launch(void* const* d_in, const int* in_sizes, int n_in,
                              void* d_out, int out_size, void* d_ws, size_t ws_size,
                              hipStream_t stream) {
    const float* x   = (const float*)d_in[0];
    const int*   ei  = (const int*)d_in[1];
    // d_in[2] = edge_weight, unused
    const int*   bat = (const int*)d_in[3];
    const float* W[3]  = {(const float*)d_in[4],  (const float*)d_in[8],  (const float*)d_in[12]};
    const float* As[3] = {(const float*)d_in[5],  (const float*)d_in[9],  (const float*)d_in[13]};
    const float* Ad[3] = {(const float*)d_in[6],  (const float*)d_in[10], (const float*)d_in[14]};
    const float* B[3]  = {(const float*)d_in[7],  (const float*)d_in[11], (const float*)d_in[15]};
    float* outp = (float*)d_out;

    // workspace layout
    char* w = (char*)d_ws;
    float* bufA   = (float*)w;  w += (size_t)N_NODES * 128 * 4;
    float* bufB   = (float*)w;  w += (size_t)N_NODES * 128 * 4;
    float* alS    = (float*)w;  w += (size_t)N_NODES * 4 * 4;
    float* alD    = (float*)w;  w += (size_t)N_NODES * 4 * 4;
    int* row_ptr  = (int*)w;    w += ((size_t)N_NODES + 4) * 4;
    int* cnts     = (int*)w;    w += (size_t)N_NODES * 4;
    int* fill     = (int*)w;    w += (size_t)N_NODES * 4;
    int* col_src  = (int*)w;    w += (size_t)ETOT * 4;
    int* bsum     = (int*)w;    w += 512;
    float* sums   = (float*)w;  w += (size_t)NGRAPH * 128 * 4;
    int* cntg     = (int*)w;    w += (size_t)NGRAPH * 4;

    // ---- CSR build (shared by all 3 layers)
    hipMemsetAsync(cnts, 0, (size_t)N_NODES * 4, stream);
    hipMemsetAsync(fill, 0, (size_t)N_NODES * 4, stream);
    hist_kernel<<<(ETOT + 255) / 256, 256, 0, stream>>>(ei, cnts);
    scan1_kernel<<<(N_NODES + 1023) / 1024, 256, 0, stream>>>(cnts, row_ptr, bsum, N_NODES);
    scan2_kernel<<<1, 128, 0, stream>>>(bsum, (N_NODES + 1023) / 1024);
    scan3_kernel<<<(N_NODES + 256) / 256, 256, 0, stream>>>(row_ptr, bsum, N_NODES);
    scatter_kernel<<<(ETOT + 255) / 256, 256, 0, stream>>>(ei, row_ptr, fill, col_src);

    const int gemm_grid = (N_NODES + 63) / 64;
    const int al_grid   = (N_NODES * 4 + 255) / 256;
    const int agg_grid  = (N_NODES + 3) / 4;       // 4 waves per 256-thread block

    // ---- layer 0 (in=64) + relu
    gemm_kernel<64><<<gemm_grid, 128, 0, stream>>>(x, W[0], bufB, N_NODES);
    al_kernel<<<al_grid, 256, 0, stream>>>(bufB, As[0], Ad[0], alS, alD, N_NODES);
    aggregate_kernel<<<agg_grid, 256, 0, stream>>>(bufB, alS, alD, row_ptr, col_src,
                                                   B[0], bufA, N_NODES, 1);
    // ---- layer 1 (in=128) + relu
    gemm_kernel<128><<<gemm_grid, 128, 0, stream>>>(bufA, W[1], bufB, N_NODES);
    al_kernel<<<al_grid, 256, 0, stream>>>(bufB, As[1], Ad[1], alS, alD, N_NODES);
    aggregate_kernel<<<agg_grid, 256, 0, stream>>>(bufB, alS, alD, row_ptr, col_src,
                                                   B[1], bufA, N_NODES, 1);
    // ---- layer 2 (in=128), no relu
    gemm_kernel<128><<<gemm_grid, 128, 0, stream>>>(bufA, W[2], bufB, N_NODES);
    al_kernel<<<al_grid, 256, 0, stream>>>(bufB, As[2], Ad[2], alS, alD, N_NODES);
    aggregate_kernel<<<agg_grid, 256, 0, stream>>>(bufB, alS, alD, row_ptr, col_src,
                                                   B[2], bufA, N_NODES, 0);

    // ---- global mean pool
    hipMemsetAsync(sums, 0, (size_t)NGRAPH * 128 * 4, stream);
    hipMemsetAsync(cntg, 0, (size_t)NGRAPH * 4, stream);
    pool_kernel<<<(N_NODES + 511) / 512, 128, 0, stream>>>(bufA, bat, sums, N_NODES);
    cnt_kernel<<<(N_NODES + 255) / 256, 256, 0, stream>>>(bat, cntg, N_NODES);
    div_kernel<<<(NGRAPH * 128 + 255) / 256, 256, 0, stream>>>(sums, cntg, outp);
}

// Round 3
// 888.805 us; speedup vs baseline: 1.1683x; 1.1683x over previous
//
#include <hip/hip_runtime.h>
#include <hip/hip_bf16.h>

#define N_NODES 100000
#define N_EDGES 800000
#define ETOT    900000   // N_EDGES + N_NODES self-loops
#define NGRAPH  256

// ---------------------------------------------------------------- CSR build
__global__ void hist_kernel(const int* __restrict__ ei, int* __restrict__ cnts) {
    int e = blockIdx.x * blockDim.x + threadIdx.x;
    if (e >= ETOT) return;
    int dst = (e < N_EDGES) ? ei[N_EDGES + e] : (e - N_EDGES);
    atomicAdd(&cnts[dst], 1);
}

__global__ void scan1_kernel(const int* __restrict__ cnts, int* __restrict__ row_ptr,
                             int* __restrict__ bsum, int n) {
    __shared__ int sdata[256];
    int tid = threadIdx.x;
    int base = blockIdx.x * 1024 + tid * 4;
    int v0 = (base + 0 < n) ? cnts[base + 0] : 0;
    int v1 = (base + 1 < n) ? cnts[base + 1] : 0;
    int v2 = (base + 2 < n) ? cnts[base + 2] : 0;
    int v3 = (base + 3 < n) ? cnts[base + 3] : 0;
    int ts = v0 + v1 + v2 + v3;
    sdata[tid] = ts;
    __syncthreads();
    for (int off = 1; off < 256; off <<= 1) {
        int t = (tid >= off) ? sdata[tid - off] : 0;
        __syncthreads();
        sdata[tid] += t;
        __syncthreads();
    }
    int run = sdata[tid] - ts;   // exclusive prefix for this thread
    if (base + 0 < n) row_ptr[base + 0] = run; run += v0;
    if (base + 1 < n) row_ptr[base + 1] = run; run += v1;
    if (base + 2 < n) row_ptr[base + 2] = run; run += v2;
    if (base + 3 < n) row_ptr[base + 3] = run;
    if (tid == 255) bsum[blockIdx.x] = sdata[255];
}

__global__ void scan2_kernel(int* __restrict__ bsum, int nb) {
    __shared__ int s[128];
    int tid = threadIdx.x;
    int v = (tid < nb) ? bsum[tid] : 0;
    s[tid] = v;
    __syncthreads();
    for (int off = 1; off < 128; off <<= 1) {
        int t = (tid >= off) ? s[tid - off] : 0;
        __syncthreads();
        s[tid] += t;
        __syncthreads();
    }
    if (tid < nb) bsum[tid] = s[tid] - v;   // exclusive
}

__global__ void scan3_kernel(int* __restrict__ row_ptr, const int* __restrict__ bsum, int n) {
    int i = blockIdx.x * blockDim.x + threadIdx.x;
    if (i < n) row_ptr[i] += bsum[i >> 10];
    if (i == 0) row_ptr[n] = ETOT;
}

__global__ void scatter_kernel(const int* __restrict__ ei, const int* __restrict__ row_ptr,
                               int* __restrict__ fill, int* __restrict__ col_src) {
    int e = blockIdx.x * blockDim.x + threadIdx.x;
    if (e >= ETOT) return;
    int src, dst;
    if (e < N_EDGES) { src = ei[e]; dst = ei[N_EDGES + e]; }
    else             { src = dst = e - N_EDGES; }
    int pos = atomicAdd(&fill[dst], 1);
    col_src[row_ptr[dst] + pos] = src;
}

// ---------------------------------------------------------------- GEMM  hp = h @ W^T
// block: 128 threads; tile 64 nodes x 128 outputs; thread tile 8 nodes x 8 outputs
template<int IN>
__global__ __launch_bounds__(128)
void gemm_kernel(const float* __restrict__ H, const float* __restrict__ W,
                 float* __restrict__ hp, int n_nodes) {
    __shared__ float sH[32][64 + 4];    // [kk][node]
    __shared__ float sW[32][128 + 4];   // [kk][out]
    int tid = threadIdx.x;
    int n0  = blockIdx.x * 64;
    int tx  = tid & 15;        // output group 0..15
    int ty  = tid >> 4;        // node group 0..7
    int o0  = tx * 8;
    int nn0 = ty * 8;
    float acc[8][8];
#pragma unroll
    for (int i = 0; i < 8; ++i)
#pragma unroll
        for (int j = 0; j < 8; ++j) acc[i][j] = 0.f;

    for (int k0 = 0; k0 < IN; k0 += 32) {
        // stage W chunk: 128 out x 32 k
#pragma unroll
        for (int i = 0; i < 8; ++i) {
            int idx = i * 128 + tid;         // 0..1023 float4 units
            int o   = idx >> 3;
            int k4  = (idx & 7) * 4;
            float4 w = *reinterpret_cast<const float4*>(W + (size_t)o * IN + k0 + k4);
            sW[k4 + 0][o] = w.x; sW[k4 + 1][o] = w.y;
            sW[k4 + 2][o] = w.z; sW[k4 + 3][o] = w.w;
        }
        // stage H chunk: 64 nodes x 32 k
#pragma unroll
        for (int i = 0; i < 4; ++i) {
            int idx = i * 128 + tid;         // 0..511 float4 units
            int nn  = idx >> 3;
            int k4  = (idx & 7) * 4;
            int nidx = n0 + nn;
            float4 h = make_float4(0.f, 0.f, 0.f, 0.f);
            if (nidx < n_nodes)
                h = *reinterpret_cast<const float4*>(H + (size_t)nidx * IN + k0 + k4);
            sH[k4 + 0][nn] = h.x; sH[k4 + 1][nn] = h.y;
            sH[k4 + 2][nn] = h.z; sH[k4 + 3][nn] = h.w;
        }
        __syncthreads();
#pragma unroll 8
        for (int kk = 0; kk < 32; ++kk) {
            float4 ha = *reinterpret_cast<float4*>(&sH[kk][nn0]);
            float4 hb = *reinterpret_cast<float4*>(&sH[kk][nn0 + 4]);
            float4 wa = *reinterpret_cast<float4*>(&sW[kk][o0]);
            float4 wb = *reinterpret_cast<float4*>(&sW[kk][o0 + 4]);
            float hv[8] = {ha.x, ha.y, ha.z, ha.w, hb.x, hb.y, hb.z, hb.w};
            float wv[8] = {wa.x, wa.y, wa.z, wa.w, wb.x, wb.y, wb.z, wb.w};
#pragma unroll
            for (int i = 0; i < 8; ++i)
#pragma unroll
                for (int j = 0; j < 8; ++j) acc[i][j] += hv[i] * wv[j];
        }
        __syncthreads();
    }
#pragma unroll
    for (int i = 0; i < 8; ++i) {
        int nn = n0 + nn0 + i;
        if (nn < n_nodes) {
            float4 r0 = make_float4(acc[i][0], acc[i][1], acc[i][2], acc[i][3]);
            float4 r1 = make_float4(acc[i][4], acc[i][5], acc[i][6], acc[i][7]);
            *reinterpret_cast<float4*>(hp + (size_t)nn * 128 + o0)     = r0;
            *reinterpret_cast<float4*>(hp + (size_t)nn * 128 + o0 + 4) = r1;
        }
    }
}

// ---------------------------------------------------------------- attention logits per node
__global__ void al_kernel(const float* __restrict__ hp, const float* __restrict__ a_src,
                          const float* __restrict__ a_dst, float* __restrict__ al_s,
                          float* __restrict__ al_d, int n_nodes) {
    int gid = blockIdx.x * blockDim.x + threadIdx.x;   // one per (node, head)
    int n = gid >> 2, h = gid & 3;
    if (n >= n_nodes) return;
    const float4* hp4 = reinterpret_cast<const float4*>(hp + (size_t)n * 128 + h * 32);
    const float4* as4 = reinterpret_cast<const float4*>(a_src + h * 32);
    const float4* ad4 = reinterpret_cast<const float4*>(a_dst + h * 32);
    float ss = 0.f, sd = 0.f;
#pragma unroll
    for (int i = 0; i < 8; ++i) {
        float4 v = hp4[i], a = as4[i], d = ad4[i];
        ss += v.x * a.x + v.y * a.y + v.z * a.z + v.w * a.w;
        sd += v.x * d.x + v.y * d.y + v.z * d.z + v.w * d.w;
    }
    al_s[gid] = ss;
    al_d[gid] = sd;
}

// ---------------------------------------------------------------- edge aggregation (one wave per dst)
// software-pipelined: col_src prefetched one edge ahead so the al_s / hp-row
// loads at the top of each iteration use an already-available src index
__global__ void aggregate_kernel(const float* __restrict__ hp,
                                 const float* __restrict__ al_s,
                                 const float* __restrict__ al_d,
                                 const int* __restrict__ row_ptr,
                                 const int* __restrict__ col_src,
                                 const float* __restrict__ bias,
                                 float* __restrict__ out,
                                 int n_nodes, int do_relu) {
    int wv   = (blockIdx.x * blockDim.x + threadIdx.x) >> 6;
    int lane = threadIdx.x & 63;
    if (wv >= n_nodes) return;
    int d    = wv;
    int head = lane >> 4;                       // lanes 0-15 head0 ... 48-63 head3
    float ald = al_d[d * 4 + head];
    int beg = row_ptr[d], end = row_ptr[d + 1];
    float m = -INFINITY, s = 0.f, acc0 = 0.f, acc1 = 0.f;
    int src = col_src[beg];                     // self-loops guarantee beg < end
    for (int j = beg; j < end; ++j) {
        int nsrc = (j + 1 < end) ? col_src[j + 1] : 0;   // prefetch next index
        float als = al_s[src * 4 + head];
        float2 v  = reinterpret_cast<const float2*>(hp + (size_t)src * 128)[lane];
        float e = als + ald;
        e = (e > 0.f) ? e : 0.2f * e;           // leaky_relu 0.2
        float nm    = fmaxf(m, e);
        float scale = __expf(m - nm);           // first iter: exp(-inf)=0
        float p     = __expf(e - nm);
        s = s * scale + p;
        acc0 = acc0 * scale + p * v.x;
        acc1 = acc1 * scale + p * v.y;
        m = nm;
        src = nsrc;
    }
    float inv = 1.f / (s + 1e-16f);
    int c0 = lane * 2;
    float o0 = acc0 * inv + bias[c0];
    float o1 = acc1 * inv + bias[c0 + 1];
    if (do_relu) { o0 = fmaxf(o0, 0.f); o1 = fmaxf(o1, 0.f); }
    reinterpret_cast<float2*>(out + (size_t)d * 128)[lane] = make_float2(o0, o1);
}

// ---------------------------------------------------------------- pooling
__global__ void pool_kernel(const float* __restrict__ feat, const int* __restrict__ batch,
                            float* __restrict__ sums, int n) {
    int c = threadIdx.x;                       // 128 channels
    int start = blockIdx.x * 512;
    int end   = min(start + 512, n);
    if (start >= end) return;
    int cur = -1;
    float acc = 0.f;
    for (int nn = start; nn < end; ++nn) {
        int g = batch[nn];                     // sorted -> rare flushes
        if (g != cur) {
            if (cur >= 0) atomicAdd(&sums[cur * 128 + c], acc);
            acc = 0.f; cur = g;
        }
        acc += feat[(size_t)nn * 128 + c];
    }
    if (cur >= 0) atomicAdd(&sums[cur * 128 + c], acc);
}

// batch is sorted: per-graph segment starts via binary search — zero atomics.
// gstart[g] = lower_bound(batch, g); gstart[NGRAPH] = n.
__global__ void gstart_kernel(const int* __restrict__ batch, int* __restrict__ gstart, int n) {
    int g = blockIdx.x * blockDim.x + threadIdx.x;
    if (g > NGRAPH) return;
    if (g == NGRAPH) { gstart[g] = n; return; }
    int lo = 0, hi = n;
    while (lo < hi) {
        int mid = (lo + hi) >> 1;
        if (batch[mid] < g) lo = mid + 1; else hi = mid;
    }
    gstart[g] = lo;
}

__global__ void div_kernel(const float* __restrict__ sums, const int* __restrict__ gstart,
                           float* __restrict__ out) {
    int i = blockIdx.x * blockDim.x + threadIdx.x;
    if (i < NGRAPH * 128) {
        int g = i >> 7;
        float c = (float)max(gstart[g + 1] - gstart[g], 1);
        out[i] = sums[i] / c;
    }
}

// ---------------------------------------------------------------- launch
extern "C" void kernel_launch(void* const* d_in, const int* in_sizes, int n_in,
                              void* d_out, int out_size, void* d_ws, size_t ws_size,
                              hipStream_t stream) {
    const float* x   = (const float*)d_in[0];
    const int*   ei  = (const int*)d_in[1];
    // d_in[2] = edge_weight, unused
    const int*   bat = (const int*)d_in[3];
    const float* W[3]  = {(const float*)d_in[4],  (const float*)d_in[8],  (const float*)d_in[12]};
    const float* As[3] = {(const float*)d_in[5],  (const float*)d_in[9],  (const float*)d_in[13]};
    const float* Ad[3] = {(const float*)d_in[6],  (const float*)d_in[10], (const float*)d_in[14]};
    const float* B[3]  = {(const float*)d_in[7],  (const float*)d_in[11], (const float*)d_in[15]};
    float* outp = (float*)d_out;

    // workspace layout
    char* w = (char*)d_ws;
    float* bufA   = (float*)w;  w += (size_t)N_NODES * 128 * 4;
    float* bufB   = (float*)w;  w += (size_t)N_NODES * 128 * 4;
    float* alS    = (float*)w;  w += (size_t)N_NODES * 4 * 4;
    float* alD    = (float*)w;  w += (size_t)N_NODES * 4 * 4;
    int* row_ptr  = (int*)w;    w += ((size_t)N_NODES + 4) * 4;
    int* cnts     = (int*)w;    w += (size_t)N_NODES * 4;
    int* fill     = (int*)w;    w += (size_t)N_NODES * 4;
    int* col_src  = (int*)w;    w += (size_t)ETOT * 4;
    int* bsum     = (int*)w;    w += 512;
    float* sums   = (float*)w;  w += (size_t)NGRAPH * 128 * 4;
    int* gstart   = (int*)w;    w += ((size_t)NGRAPH + 4) * 4;

    // ---- CSR build (shared by all 3 layers)
    hipMemsetAsync(cnts, 0, (size_t)N_NODES * 4, stream);
    hipMemsetAsync(fill, 0, (size_t)N_NODES * 4, stream);
    hist_kernel<<<(ETOT + 255) / 256, 256, 0, stream>>>(ei, cnts);
    scan1_kernel<<<(N_NODES + 1023) / 1024, 256, 0, stream>>>(cnts, row_ptr, bsum, N_NODES);
    scan2_kernel<<<1, 128, 0, stream>>>(bsum, (N_NODES + 1023) / 1024);
    scan3_kernel<<<(N_NODES + 256) / 256, 256, 0, stream>>>(row_ptr, bsum, N_NODES);
    scatter_kernel<<<(ETOT + 255) / 256, 256, 0, stream>>>(ei, row_ptr, fill, col_src);

    const int gemm_grid = (N_NODES + 63) / 64;
    const int al_grid   = (N_NODES * 4 + 255) / 256;
    const int agg_grid  = (N_NODES + 3) / 4;       // 4 waves per 256-thread block

    // ---- layer 0 (in=64) + relu
    gemm_kernel<64><<<gemm_grid, 128, 0, stream>>>(x, W[0], bufB, N_NODES);
    al_kernel<<<al_grid, 256, 0, stream>>>(bufB, As[0], Ad[0], alS, alD, N_NODES);
    aggregate_kernel<<<agg_grid, 256, 0, stream>>>(bufB, alS, alD, row_ptr, col_src,
                                                   B[0], bufA, N_NODES, 1);
    // ---- layer 1 (in=128) + relu
    gemm_kernel<128><<<gemm_grid, 128, 0, stream>>>(bufA, W[1], bufB, N_NODES);
    al_kernel<<<al_grid, 256, 0, stream>>>(bufB, As[1], Ad[1], alS, alD, N_NODES);
    aggregate_kernel<<<agg_grid, 256, 0, stream>>>(bufB, alS, alD, row_ptr, col_src,
                                                   B[1], bufA, N_NODES, 1);
    // ---- layer 2 (in=128), no relu
    gemm_kernel<128><<<gemm_grid, 128, 0, stream>>>(bufA, W[2], bufB, N_NODES);
    al_kernel<<<al_grid, 256, 0, stream>>>(bufB, As[2], Ad[2], alS, alD, N_NODES);
    aggregate_kernel<<<agg_grid, 256, 0, stream>>>(bufB, alS, alD, row_ptr, col_src,
                                                   B[2], bufA, N_NODES, 0);

    // ---- global mean pool
    hipMemsetAsync(sums, 0, (size_t)NGRAPH * 128 * 4, stream);
    gstart_kernel<<<2, 256, 0, stream>>>(bat, gstart, N_NODES);
    pool_kernel<<<(N_NODES + 511) / 512, 128, 0, stream>>>(bufA, bat, sums, N_NODES);
    div_kernel<<<(NGRAPH * 128 + 255) / 256, 256, 0, stream>>>(sums, gstart, outp);
}

// Round 4
// 736.215 us; speedup vs baseline: 1.4105x; 1.2073x over previous
//
#include <hip/hip_runtime.h>
#include <hip/hip_bf16.h>

#define N_NODES 100000
#define N_EDGES 800000
#define ETOT    900000   // N_EDGES + N_NODES self-loops
#define NGRAPH  256

// ---------------------------------------------------------------- CSR build
__global__ void hist_kernel(const int* __restrict__ ei, int* __restrict__ cnts) {
    int e = blockIdx.x * blockDim.x + threadIdx.x;
    if (e >= ETOT) return;
    int dst = (e < N_EDGES) ? ei[N_EDGES + e] : (e - N_EDGES);
    atomicAdd(&cnts[dst], 1);
}

__global__ void scan1_kernel(const int* __restrict__ cnts, int* __restrict__ row_ptr,
                             int* __restrict__ bsum, int n) {
    __shared__ int sdata[256];
    int tid = threadIdx.x;
    int base = blockIdx.x * 1024 + tid * 4;
    int v0 = (base + 0 < n) ? cnts[base + 0] : 0;
    int v1 = (base + 1 < n) ? cnts[base + 1] : 0;
    int v2 = (base + 2 < n) ? cnts[base + 2] : 0;
    int v3 = (base + 3 < n) ? cnts[base + 3] : 0;
    int ts = v0 + v1 + v2 + v3;
    sdata[tid] = ts;
    __syncthreads();
    for (int off = 1; off < 256; off <<= 1) {
        int t = (tid >= off) ? sdata[tid - off] : 0;
        __syncthreads();
        sdata[tid] += t;
        __syncthreads();
    }
    int run = sdata[tid] - ts;   // exclusive prefix for this thread
    if (base + 0 < n) row_ptr[base + 0] = run; run += v0;
    if (base + 1 < n) row_ptr[base + 1] = run; run += v1;
    if (base + 2 < n) row_ptr[base + 2] = run; run += v2;
    if (base + 3 < n) row_ptr[base + 3] = run;
    if (tid == 255) bsum[blockIdx.x] = sdata[255];
}

__global__ void scan2_kernel(int* __restrict__ bsum, int nb) {
    __shared__ int s[128];
    int tid = threadIdx.x;
    int v = (tid < nb) ? bsum[tid] : 0;
    s[tid] = v;
    __syncthreads();
    for (int off = 1; off < 128; off <<= 1) {
        int t = (tid >= off) ? s[tid - off] : 0;
        __syncthreads();
        s[tid] += t;
        __syncthreads();
    }
    if (tid < nb) bsum[tid] = s[tid] - v;   // exclusive
}

__global__ void scan3_kernel(int* __restrict__ row_ptr, const int* __restrict__ bsum, int n) {
    int i = blockIdx.x * blockDim.x + threadIdx.x;
    if (i < n) row_ptr[i] += bsum[i >> 10];
    if (i == 0) row_ptr[n] = ETOT;
}

__global__ void scatter_kernel(const int* __restrict__ ei, const int* __restrict__ row_ptr,
                               int* __restrict__ fill, int* __restrict__ col_src) {
    int e = blockIdx.x * blockDim.x + threadIdx.x;
    if (e >= ETOT) return;
    int src, dst;
    if (e < N_EDGES) { src = ei[e]; dst = ei[N_EDGES + e]; }
    else             { src = dst = e - N_EDGES; }
    int pos = atomicAdd(&fill[dst], 1);
    col_src[row_ptr[dst] + pos] = src;
}

// ---------------------------------------------------------------- GEMM  hp = h @ W^T
// 256 threads; tile 128 nodes x 128 outputs; BK=32; per-thread 8x8 via strided
// sub-tiles (tx*4 / tx*4+64) -> sW reads are 2-way bank aliased (free), sH
// reads are 16-lane broadcasts.
template<int IN>
__global__ __launch_bounds__(256)
void gemm_kernel(const float* __restrict__ H, const float* __restrict__ W,
                 float* __restrict__ hp, int n_nodes) {
    __shared__ float sH[32][132];    // [kk][node]
    __shared__ float sW[32][132];    // [kk][out]
    int tid = threadIdx.x;
    int n0  = blockIdx.x * 128;
    int tx  = tid & 15;        // output group
    int ty  = tid >> 4;        // node group (0..15)
    float acc[8][8];
#pragma unroll
    for (int i = 0; i < 8; ++i)
#pragma unroll
        for (int j = 0; j < 8; ++j) acc[i][j] = 0.f;

    for (int k0 = 0; k0 < IN; k0 += 32) {
        // stage W chunk: 128 out x 32 k   (1024 float4 units, 4 passes)
#pragma unroll
        for (int it = 0; it < 4; ++it) {
            int idx = it * 256 + tid;
            int o   = idx >> 3;
            int k4  = (idx & 7) * 4;
            float4 w = *reinterpret_cast<const float4*>(W + (size_t)o * IN + k0 + k4);
            sW[k4 + 0][o] = w.x; sW[k4 + 1][o] = w.y;
            sW[k4 + 2][o] = w.z; sW[k4 + 3][o] = w.w;
        }
        // stage H chunk: 128 nodes x 32 k
#pragma unroll
        for (int it = 0; it < 4; ++it) {
            int idx = it * 256 + tid;
            int nn  = idx >> 3;
            int k4  = (idx & 7) * 4;
            int nidx = n0 + nn;
            float4 h = make_float4(0.f, 0.f, 0.f, 0.f);
            if (nidx < n_nodes)
                h = *reinterpret_cast<const float4*>(H + (size_t)nidx * IN + k0 + k4);
            sH[k4 + 0][nn] = h.x; sH[k4 + 1][nn] = h.y;
            sH[k4 + 2][nn] = h.z; sH[k4 + 3][nn] = h.w;
        }
        __syncthreads();
#pragma unroll 4
        for (int kk = 0; kk < 32; ++kk) {
            float4 h0 = *reinterpret_cast<float4*>(&sH[kk][ty * 4]);
            float4 h1 = *reinterpret_cast<float4*>(&sH[kk][ty * 4 + 64]);
            float4 w0 = *reinterpret_cast<float4*>(&sW[kk][tx * 4]);
            float4 w1 = *reinterpret_cast<float4*>(&sW[kk][tx * 4 + 64]);
            float hv[8] = {h0.x, h0.y, h0.z, h0.w, h1.x, h1.y, h1.z, h1.w};
            float wv[8] = {w0.x, w0.y, w0.z, w0.w, w1.x, w1.y, w1.z, w1.w};
#pragma unroll
            for (int i = 0; i < 8; ++i)
#pragma unroll
                for (int j = 0; j < 8; ++j) acc[i][j] += hv[i] * wv[j];
        }
        __syncthreads();
    }
#pragma unroll
    for (int i = 0; i < 8; ++i) {
        int nn = n0 + ((i < 4) ? (ty * 4 + i) : (64 + ty * 4 + i - 4));
        if (nn < n_nodes) {
            float4 r0 = make_float4(acc[i][0], acc[i][1], acc[i][2], acc[i][3]);
            float4 r1 = make_float4(acc[i][4], acc[i][5], acc[i][6], acc[i][7]);
            *reinterpret_cast<float4*>(hp + (size_t)nn * 128 + tx * 4)      = r0;
            *reinterpret_cast<float4*>(hp + (size_t)nn * 128 + tx * 4 + 64) = r1;
        }
    }
}

// ---------------------------------------------------------------- attention logits per node
__global__ void al_kernel(const float* __restrict__ hp, const float* __restrict__ a_src,
                          const float* __restrict__ a_dst, float* __restrict__ al_s,
                          float* __restrict__ al_d, int n_nodes) {
    int gid = blockIdx.x * blockDim.x + threadIdx.x;   // one per (node, head)
    int n = gid >> 2, h = gid & 3;
    if (n >= n_nodes) return;
    const float4* hp4 = reinterpret_cast<const float4*>(hp + (size_t)n * 128 + h * 32);
    const float4* as4 = reinterpret_cast<const float4*>(a_src + h * 32);
    const float4* ad4 = reinterpret_cast<const float4*>(a_dst + h * 32);
    float ss = 0.f, sd = 0.f;
#pragma unroll
    for (int i = 0; i < 8; ++i) {
        float4 v = hp4[i], a = as4[i], d = ad4[i];
        ss += v.x * a.x + v.y * a.y + v.z * a.z + v.w * a.w;
        sd += v.x * d.x + v.y * d.y + v.z * d.z + v.w * d.w;
    }
    al_s[gid] = ss;
    al_d[gid] = sd;
}

// ---------------------------------------------------------------- edge aggregation (one wave per dst)
// software-pipelined: col_src prefetched one edge ahead so the al_s / hp-row
// loads at the top of each iteration use an already-available src index
__global__ void aggregate_kernel(const float* __restrict__ hp,
                                 const float* __restrict__ al_s,
                                 const float* __restrict__ al_d,
                                 const int* __restrict__ row_ptr,
                                 const int* __restrict__ col_src,
                                 const float* __restrict__ bias,
                                 float* __restrict__ out,
                                 int n_nodes, int do_relu) {
    int wv   = (blockIdx.x * blockDim.x + threadIdx.x) >> 6;
    int lane = threadIdx.x & 63;
    if (wv >= n_nodes) return;
    int d    = wv;
    int head = lane >> 4;                       // lanes 0-15 head0 ... 48-63 head3
    float ald = al_d[d * 4 + head];
    int beg = row_ptr[d], end = row_ptr[d + 1];
    float m = -INFINITY, s = 0.f, acc0 = 0.f, acc1 = 0.f;
    int src = col_src[beg];                     // self-loops guarantee beg < end
    for (int j = beg; j < end; ++j) {
        int nsrc = (j + 1 < end) ? col_src[j + 1] : 0;   // prefetch next index
        float als = al_s[src * 4 + head];
        float2 v  = reinterpret_cast<const float2*>(hp + (size_t)src * 128)[lane];
        float e = als + ald;
        e = (e > 0.f) ? e : 0.2f * e;           // leaky_relu 0.2
        float nm    = fmaxf(m, e);
        float scale = __expf(m - nm);           // first iter: exp(-inf)=0
        float p     = __expf(e - nm);
        s = s * scale + p;
        acc0 = acc0 * scale + p * v.x;
        acc1 = acc1 * scale + p * v.y;
        m = nm;
        src = nsrc;
    }
    float inv = 1.f / (s + 1e-16f);
    int c0 = lane * 2;
    float o0 = acc0 * inv + bias[c0];
    float o1 = acc1 * inv + bias[c0 + 1];
    if (do_relu) { o0 = fmaxf(o0, 0.f); o1 = fmaxf(o1, 0.f); }
    reinterpret_cast<float2*>(out + (size_t)d * 128)[lane] = make_float2(o0, o1);
}

// ---------------------------------------------------------------- pooling
// 64 nodes per block -> 1563 blocks (parallelism); batch sorted so boundary
// flushes are rare (~1.1 atomics per thread).
__global__ void pool_kernel(const float* __restrict__ feat, const int* __restrict__ batch,
                            float* __restrict__ sums, int n) {
    int c = threadIdx.x;                       // 128 channels
    int start = blockIdx.x * 64;
    int end   = min(start + 64, n);
    if (start >= end) return;
    int cur = batch[start];
    float acc = 0.f;
    for (int nn = start; nn < end; ++nn) {
        int g = batch[nn];
        if (g != cur) {
            atomicAdd(&sums[cur * 128 + c], acc);
            acc = 0.f; cur = g;
        }
        acc += feat[(size_t)nn * 128 + c];
    }
    atomicAdd(&sums[cur * 128 + c], acc);
}

// batch is sorted: per-graph segment starts via binary search — zero atomics.
// gstart[g] = lower_bound(batch, g); gstart[NGRAPH] = n.
__global__ void gstart_kernel(const int* __restrict__ batch, int* __restrict__ gstart, int n) {
    int g = blockIdx.x * blockDim.x + threadIdx.x;
    if (g > NGRAPH) return;
    if (g == NGRAPH) { gstart[g] = n; return; }
    int lo = 0, hi = n;
    while (lo < hi) {
        int mid = (lo + hi) >> 1;
        if (batch[mid] < g) lo = mid + 1; else hi = mid;
    }
    gstart[g] = lo;
}

__global__ void div_kernel(const float* __restrict__ sums, const int* __restrict__ gstart,
                           float* __restrict__ out) {
    int i = blockIdx.x * blockDim.x + threadIdx.x;
    if (i < NGRAPH * 128) {
        int g = i >> 7;
        float c = (float)max(gstart[g + 1] - gstart[g], 1);
        out[i] = sums[i] / c;
    }
}

// ---------------------------------------------------------------- launch
extern "C" void kernel_launch(void* const* d_in, const int* in_sizes, int n_in,
                              void* d_out, int out_size, void* d_ws, size_t ws_size,
                              hipStream_t stream) {
    const float* x   = (const float*)d_in[0];
    const int*   ei  = (const int*)d_in[1];
    // d_in[2] = edge_weight, unused
    const int*   bat = (const int*)d_in[3];
    const float* W[3]  = {(const float*)d_in[4],  (const float*)d_in[8],  (const float*)d_in[12]};
    const float* As[3] = {(const float*)d_in[5],  (const float*)d_in[9],  (const float*)d_in[13]};
    const float* Ad[3] = {(const float*)d_in[6],  (const float*)d_in[10], (const float*)d_in[14]};
    const float* B[3]  = {(const float*)d_in[7],  (const float*)d_in[11], (const float*)d_in[15]};
    float* outp = (float*)d_out;

    // workspace layout
    char* w = (char*)d_ws;
    float* bufA   = (float*)w;  w += (size_t)N_NODES * 128 * 4;
    float* bufB   = (float*)w;  w += (size_t)N_NODES * 128 * 4;
    float* alS    = (float*)w;  w += (size_t)N_NODES * 4 * 4;
    float* alD    = (float*)w;  w += (size_t)N_NODES * 4 * 4;
    int* row_ptr  = (int*)w;    w += ((size_t)N_NODES + 4) * 4;
    int* cnts     = (int*)w;    w += (size_t)N_NODES * 4;
    int* fill     = (int*)w;    w += (size_t)N_NODES * 4;
    int* col_src  = (int*)w;    w += (size_t)ETOT * 4;
    int* bsum     = (int*)w;    w += 512;
    float* sums   = (float*)w;  w += (size_t)NGRAPH * 128 * 4;
    int* gstart   = (int*)w;    w += ((size_t)NGRAPH + 4) * 4;

    // ---- CSR build (shared by all 3 layers)
    hipMemsetAsync(cnts, 0, (size_t)N_NODES * 4, stream);
    hipMemsetAsync(fill, 0, (size_t)N_NODES * 4, stream);
    hist_kernel<<<(ETOT + 255) / 256, 256, 0, stream>>>(ei, cnts);
    scan1_kernel<<<(N_NODES + 1023) / 1024, 256, 0, stream>>>(cnts, row_ptr, bsum, N_NODES);
    scan2_kernel<<<1, 128, 0, stream>>>(bsum, (N_NODES + 1023) / 1024);
    scan3_kernel<<<(N_NODES + 256) / 256, 256, 0, stream>>>(row_ptr, bsum, N_NODES);
    scatter_kernel<<<(ETOT + 255) / 256, 256, 0, stream>>>(ei, row_ptr, fill, col_src);

    const int gemm_grid = (N_NODES + 127) / 128;
    const int al_grid   = (N_NODES * 4 + 255) / 256;
    const int agg_grid  = (N_NODES + 3) / 4;       // 4 waves per 256-thread block

    // ---- layer 0 (in=64) + relu
    gemm_kernel<64><<<gemm_grid, 256, 0, stream>>>(x, W[0], bufB, N_NODES);
    al_kernel<<<al_grid, 256, 0, stream>>>(bufB, As[0], Ad[0], alS, alD, N_NODES);
    aggregate_kernel<<<agg_grid, 256, 0, stream>>>(bufB, alS, alD, row_ptr, col_src,
                                                   B[0], bufA, N_NODES, 1);
    // ---- layer 1 (in=128) + relu
    gemm_kernel<128><<<gemm_grid, 256, 0, stream>>>(bufA, W[1], bufB, N_NODES);
    al_kernel<<<al_grid, 256, 0, stream>>>(bufB, As[1], Ad[1], alS, alD, N_NODES);
    aggregate_kernel<<<agg_grid, 256, 0, stream>>>(bufB, alS, alD, row_ptr, col_src,
                                                   B[1], bufA, N_NODES, 1);
    // ---- layer 2 (in=128), no relu
    gemm_kernel<128><<<gemm_grid, 256, 0, stream>>>(bufA, W[2], bufB, N_NODES);
    al_kernel<<<al_grid, 256, 0, stream>>>(bufB, As[2], Ad[2], alS, alD, N_NODES);
    aggregate_kernel<<<agg_grid, 256, 0, stream>>>(bufB, alS, alD, row_ptr, col_src,
                                                   B[2], bufA, N_NODES, 0);

    // ---- global mean pool
    hipMemsetAsync(sums, 0, (size_t)NGRAPH * 128 * 4, stream);
    gstart_kernel<<<2, 256, 0, stream>>>(bat, gstart, N_NODES);
    pool_kernel<<<(N_NODES + 63) / 64, 128, 0, stream>>>(bufA, bat, sums, N_NODES);
    div_kernel<<<(NGRAPH * 128 + 255) / 256, 256, 0, stream>>>(sums, gstart, outp);
}

// Round 5
// 648.203 us; speedup vs baseline: 1.6020x; 1.1358x over previous
//
#include <hip/hip_runtime.h>
#include <hip/hip_bf16.h>

#define N_NODES 100000
#define N_EDGES 800000
#define ETOT    900000   // N_EDGES + N_NODES self-loops
#define NGRAPH  256

// ---------------------------------------------------------------- CSR build
__global__ void hist_kernel(const int* __restrict__ ei, int* __restrict__ cnts) {
    int e = blockIdx.x * blockDim.x + threadIdx.x;
    if (e >= ETOT) return;
    int dst = (e < N_EDGES) ? ei[N_EDGES + e] : (e - N_EDGES);
    atomicAdd(&cnts[dst], 1);
}

__global__ void scan1_kernel(const int* __restrict__ cnts, int* __restrict__ row_ptr,
                             int* __restrict__ bsum, int n) {
    __shared__ int sdata[256];
    int tid = threadIdx.x;
    int base = blockIdx.x * 1024 + tid * 4;
    int v0 = (base + 0 < n) ? cnts[base + 0] : 0;
    int v1 = (base + 1 < n) ? cnts[base + 1] : 0;
    int v2 = (base + 2 < n) ? cnts[base + 2] : 0;
    int v3 = (base + 3 < n) ? cnts[base + 3] : 0;
    int ts = v0 + v1 + v2 + v3;
    sdata[tid] = ts;
    __syncthreads();
    for (int off = 1; off < 256; off <<= 1) {
        int t = (tid >= off) ? sdata[tid - off] : 0;
        __syncthreads();
        sdata[tid] += t;
        __syncthreads();
    }
    int run = sdata[tid] - ts;   // exclusive prefix for this thread
    if (base + 0 < n) row_ptr[base + 0] = run; run += v0;
    if (base + 1 < n) row_ptr[base + 1] = run; run += v1;
    if (base + 2 < n) row_ptr[base + 2] = run; run += v2;
    if (base + 3 < n) row_ptr[base + 3] = run;
    if (tid == 255) bsum[blockIdx.x] = sdata[255];
}

__global__ void scan2_kernel(int* __restrict__ bsum, int nb) {
    __shared__ int s[128];
    int tid = threadIdx.x;
    int v = (tid < nb) ? bsum[tid] : 0;
    s[tid] = v;
    __syncthreads();
    for (int off = 1; off < 128; off <<= 1) {
        int t = (tid >= off) ? s[tid - off] : 0;
        __syncthreads();
        s[tid] += t;
        __syncthreads();
    }
    if (tid < nb) bsum[tid] = s[tid] - v;   // exclusive
}

__global__ void scan3_kernel(int* __restrict__ row_ptr, const int* __restrict__ bsum, int n) {
    int i = blockIdx.x * blockDim.x + threadIdx.x;
    if (i < n) row_ptr[i] += bsum[i >> 10];
    if (i == 0) row_ptr[n] = ETOT;
}

__global__ void scatter_kernel(const int* __restrict__ ei, const int* __restrict__ row_ptr,
                               int* __restrict__ fill, int* __restrict__ col_src) {
    int e = blockIdx.x * blockDim.x + threadIdx.x;
    if (e >= ETOT) return;
    int src, dst;
    if (e < N_EDGES) { src = ei[e]; dst = ei[N_EDGES + e]; }
    else             { src = dst = e - N_EDGES; }
    int pos = atomicAdd(&fill[dst], 1);
    col_src[row_ptr[dst] + pos] = src;
}

// ---------------------------------------------------------------- GEMM  hp = h @ W^T
// 256 threads; tile 128 nodes x 128 outputs; BK=32; per-thread 8x8 via strided
// sub-tiles (tx*4 / tx*4+64) -> sW reads are 2-way bank aliased (free), sH
// reads are 16-lane broadcasts.
template<int IN>
__global__ __launch_bounds__(256)
void gemm_kernel(const float* __restrict__ H, const float* __restrict__ W,
                 float* __restrict__ hp, int n_nodes) {
    __shared__ float sH[32][132];    // [kk][node]
    __shared__ float sW[32][132];    // [kk][out]
    int tid = threadIdx.x;
    int n0  = blockIdx.x * 128;
    int tx  = tid & 15;        // output group
    int ty  = tid >> 4;        // node group (0..15)
    float acc[8][8];
#pragma unroll
    for (int i = 0; i < 8; ++i)
#pragma unroll
        for (int j = 0; j < 8; ++j) acc[i][j] = 0.f;

    for (int k0 = 0; k0 < IN; k0 += 32) {
        // stage W chunk: 128 out x 32 k   (1024 float4 units, 4 passes)
#pragma unroll
        for (int it = 0; it < 4; ++it) {
            int idx = it * 256 + tid;
            int o   = idx >> 3;
            int k4  = (idx & 7) * 4;
            float4 w = *reinterpret_cast<const float4*>(W + (size_t)o * IN + k0 + k4);
            sW[k4 + 0][o] = w.x; sW[k4 + 1][o] = w.y;
            sW[k4 + 2][o] = w.z; sW[k4 + 3][o] = w.w;
        }
        // stage H chunk: 128 nodes x 32 k
#pragma unroll
        for (int it = 0; it < 4; ++it) {
            int idx = it * 256 + tid;
            int nn  = idx >> 3;
            int k4  = (idx & 7) * 4;
            int nidx = n0 + nn;
            float4 h = make_float4(0.f, 0.f, 0.f, 0.f);
            if (nidx < n_nodes)
                h = *reinterpret_cast<const float4*>(H + (size_t)nidx * IN + k0 + k4);
            sH[k4 + 0][nn] = h.x; sH[k4 + 1][nn] = h.y;
            sH[k4 + 2][nn] = h.z; sH[k4 + 3][nn] = h.w;
        }
        __syncthreads();
#pragma unroll 4
        for (int kk = 0; kk < 32; ++kk) {
            float4 h0 = *reinterpret_cast<float4*>(&sH[kk][ty * 4]);
            float4 h1 = *reinterpret_cast<float4*>(&sH[kk][ty * 4 + 64]);
            float4 w0 = *reinterpret_cast<float4*>(&sW[kk][tx * 4]);
            float4 w1 = *reinterpret_cast<float4*>(&sW[kk][tx * 4 + 64]);
            float hv[8] = {h0.x, h0.y, h0.z, h0.w, h1.x, h1.y, h1.z, h1.w};
            float wv[8] = {w0.x, w0.y, w0.z, w0.w, w1.x, w1.y, w1.z, w1.w};
#pragma unroll
            for (int i = 0; i < 8; ++i)
#pragma unroll
                for (int j = 0; j < 8; ++j) acc[i][j] += hv[i] * wv[j];
        }
        __syncthreads();
    }
#pragma unroll
    for (int i = 0; i < 8; ++i) {
        int nn = n0 + ((i < 4) ? (ty * 4 + i) : (64 + ty * 4 + i - 4));
        if (nn < n_nodes) {
            float4 r0 = make_float4(acc[i][0], acc[i][1], acc[i][2], acc[i][3]);
            float4 r1 = make_float4(acc[i][4], acc[i][5], acc[i][6], acc[i][7]);
            *reinterpret_cast<float4*>(hp + (size_t)nn * 128 + tx * 4)      = r0;
            *reinterpret_cast<float4*>(hp + (size_t)nn * 128 + tx * 4 + 64) = r1;
        }
    }
}

// ---------------------------------------------------------------- attention logits per node
__global__ void al_kernel(const float* __restrict__ hp, const float* __restrict__ a_src,
                          const float* __restrict__ a_dst, float* __restrict__ al_s,
                          float* __restrict__ al_d, int n_nodes) {
    int gid = blockIdx.x * blockDim.x + threadIdx.x;   // one per (node, head)
    int n = gid >> 2, h = gid & 3;
    if (n >= n_nodes) return;
    const float4* hp4 = reinterpret_cast<const float4*>(hp + (size_t)n * 128 + h * 32);
    const float4* as4 = reinterpret_cast<const float4*>(a_src + h * 32);
    const float4* ad4 = reinterpret_cast<const float4*>(a_dst + h * 32);
    float ss = 0.f, sd = 0.f;
#pragma unroll
    for (int i = 0; i < 8; ++i) {
        float4 v = hp4[i], a = as4[i], d = ad4[i];
        ss += v.x * a.x + v.y * a.y + v.z * a.z + v.w * a.w;
        sd += v.x * d.x + v.y * d.y + v.z * d.z + v.w * d.w;
    }
    al_s[gid] = ss;
    al_d[gid] = sd;
}

// ---------------------------------------------------------------- edge aggregation (one wave per dst)
// 4-wide unrolled online softmax: all 8 gather loads of a group issued before
// any consumption -> 4x the memory-level parallelism of the serial loop, and
// one rescale exp + one max-tree per 4 edges instead of per edge.
__global__ void aggregate_kernel(const float* __restrict__ hp,
                                 const float* __restrict__ al_s,
                                 const float* __restrict__ al_d,
                                 const int* __restrict__ row_ptr,
                                 const int* __restrict__ col_src,
                                 const float* __restrict__ bias,
                                 float* __restrict__ out,
                                 int n_nodes, int do_relu) {
    int wv   = (blockIdx.x * blockDim.x + threadIdx.x) >> 6;
    int lane = threadIdx.x & 63;
    if (wv >= n_nodes) return;
    int d    = wv;
    int head = lane >> 4;                       // lanes 0-15 head0 ... 48-63 head3
    float ald = al_d[d * 4 + head];
    int beg = row_ptr[d], end = row_ptr[d + 1];
    const float2* hpl = reinterpret_cast<const float2*>(hp) + lane;   // + src*64
    float m = -INFINITY, s = 0.f, acc0 = 0.f, acc1 = 0.f;

    int j = beg;
    for (; j + 3 < end; j += 4) {
        int s0 = col_src[j + 0];
        int s1 = col_src[j + 1];
        int s2 = col_src[j + 2];
        int s3 = col_src[j + 3];
        float al0 = al_s[s0 * 4 + head];
        float al1 = al_s[s1 * 4 + head];
        float al2 = al_s[s2 * 4 + head];
        float al3 = al_s[s3 * 4 + head];
        float2 v0 = hpl[(size_t)s0 * 64];
        float2 v1 = hpl[(size_t)s1 * 64];
        float2 v2 = hpl[(size_t)s2 * 64];
        float2 v3 = hpl[(size_t)s3 * 64];
        float e0 = al0 + ald; e0 = (e0 > 0.f) ? e0 : 0.2f * e0;
        float e1 = al1 + ald; e1 = (e1 > 0.f) ? e1 : 0.2f * e1;
        float e2 = al2 + ald; e2 = (e2 > 0.f) ? e2 : 0.2f * e2;
        float e3 = al3 + ald; e3 = (e3 > 0.f) ? e3 : 0.2f * e3;
        float nm = fmaxf(fmaxf(fmaxf(e0, e1), fmaxf(e2, e3)), m);
        float sc = __expf(m - nm);              // first group: exp(-inf)=0
        float p0 = __expf(e0 - nm);
        float p1 = __expf(e1 - nm);
        float p2 = __expf(e2 - nm);
        float p3 = __expf(e3 - nm);
        s    = s    * sc + ((p0 + p1) + (p2 + p3));
        acc0 = acc0 * sc + ((p0 * v0.x + p1 * v1.x) + (p2 * v2.x + p3 * v3.x));
        acc1 = acc1 * sc + ((p0 * v0.y + p1 * v1.y) + (p2 * v2.y + p3 * v3.y));
        m = nm;
    }
    for (; j < end; ++j) {                      // tail (< 4 edges)
        int src = col_src[j];
        float als = al_s[src * 4 + head];
        float2 v  = hpl[(size_t)src * 64];
        float e = als + ald;
        e = (e > 0.f) ? e : 0.2f * e;
        float nm    = fmaxf(m, e);
        float scale = __expf(m - nm);
        float p     = __expf(e - nm);
        s    = s    * scale + p;
        acc0 = acc0 * scale + p * v.x;
        acc1 = acc1 * scale + p * v.y;
        m = nm;
    }
    float inv = 1.f / (s + 1e-16f);
    int c0 = lane * 2;
    float o0 = acc0 * inv + bias[c0];
    float o1 = acc1 * inv + bias[c0 + 1];
    if (do_relu) { o0 = fmaxf(o0, 0.f); o1 = fmaxf(o1, 0.f); }
    reinterpret_cast<float2*>(out + (size_t)d * 128)[lane] = make_float2(o0, o1);
}

// ---------------------------------------------------------------- pooling
// 64 nodes per block -> 1563 blocks (parallelism); batch sorted so boundary
// flushes are rare (~1.1 atomics per thread).
__global__ void pool_kernel(const float* __restrict__ feat, const int* __restrict__ batch,
                            float* __restrict__ sums, int n) {
    int c = threadIdx.x;                       // 128 channels
    int start = blockIdx.x * 64;
    int end   = min(start + 64, n);
    if (start >= end) return;
    int cur = batch[start];
    float acc = 0.f;
    for (int nn = start; nn < end; ++nn) {
        int g = batch[nn];
        if (g != cur) {
            atomicAdd(&sums[cur * 128 + c], acc);
            acc = 0.f; cur = g;
        }
        acc += feat[(size_t)nn * 128 + c];
    }
    atomicAdd(&sums[cur * 128 + c], acc);
}

// batch is sorted: per-graph segment starts via binary search — zero atomics.
__global__ void gstart_kernel(const int* __restrict__ batch, int* __restrict__ gstart, int n) {
    int g = blockIdx.x * blockDim.x + threadIdx.x;
    if (g > NGRAPH) return;
    if (g == NGRAPH) { gstart[g] = n; return; }
    int lo = 0, hi = n;
    while (lo < hi) {
        int mid = (lo + hi) >> 1;
        if (batch[mid] < g) lo = mid + 1; else hi = mid;
    }
    gstart[g] = lo;
}

__global__ void div_kernel(const float* __restrict__ sums, const int* __restrict__ gstart,
                           float* __restrict__ out) {
    int i = blockIdx.x * blockDim.x + threadIdx.x;
    if (i < NGRAPH * 128) {
        int g = i >> 7;
        float c = (float)max(gstart[g + 1] - gstart[g], 1);
        out[i] = sums[i] / c;
    }
}

// ---------------------------------------------------------------- launch
extern "C" void kernel_launch(void* const* d_in, const int* in_sizes, int n_in,
                              void* d_out, int out_size, void* d_ws, size_t ws_size,
                              hipStream_t stream) {
    const float* x   = (const float*)d_in[0];
    const int*   ei  = (const int*)d_in[1];
    // d_in[2] = edge_weight, unused
    const int*   bat = (const int*)d_in[3];
    const float* W[3]  = {(const float*)d_in[4],  (const float*)d_in[8],  (const float*)d_in[12]};
    const float* As[3] = {(const float*)d_in[5],  (const float*)d_in[9],  (const float*)d_in[13]};
    const float* Ad[3] = {(const float*)d_in[6],  (const float*)d_in[10], (const float*)d_in[14]};
    const float* B[3]  = {(const float*)d_in[7],  (const float*)d_in[11], (const float*)d_in[15]};
    float* outp = (float*)d_out;

    // workspace layout
    char* w = (char*)d_ws;
    float* bufA   = (float*)w;  w += (size_t)N_NODES * 128 * 4;
    float* bufB   = (float*)w;  w += (size_t)N_NODES * 128 * 4;
    float* alS    = (float*)w;  w += (size_t)N_NODES * 4 * 4;
    float* alD    = (float*)w;  w += (size_t)N_NODES * 4 * 4;
    int* row_ptr  = (int*)w;    w += ((size_t)N_NODES + 4) * 4;
    int* cnts     = (int*)w;    w += (size_t)N_NODES * 4;
    int* fill     = (int*)w;    w += (size_t)N_NODES * 4;
    int* col_src  = (int*)w;    w += (size_t)ETOT * 4;
    int* bsum     = (int*)w;    w += 512;
    float* sums   = (float*)w;  w += (size_t)NGRAPH * 128 * 4;
    int* gstart   = (int*)w;    w += ((size_t)NGRAPH + 4) * 4;

    // ---- CSR build (shared by all 3 layers)
    hipMemsetAsync(cnts, 0, (size_t)N_NODES * 4, stream);
    hipMemsetAsync(fill, 0, (size_t)N_NODES * 4, stream);
    hist_kernel<<<(ETOT + 255) / 256, 256, 0, stream>>>(ei, cnts);
    scan1_kernel<<<(N_NODES + 1023) / 1024, 256, 0, stream>>>(cnts, row_ptr, bsum, N_NODES);
    scan2_kernel<<<1, 128, 0, stream>>>(bsum, (N_NODES + 1023) / 1024);
    scan3_kernel<<<(N_NODES + 256) / 256, 256, 0, stream>>>(row_ptr, bsum, N_NODES);
    scatter_kernel<<<(ETOT + 255) / 256, 256, 0, stream>>>(ei, row_ptr, fill, col_src);

    const int gemm_grid = (N_NODES + 127) / 128;
    const int al_grid   = (N_NODES * 4 + 255) / 256;
    const int agg_grid  = (N_NODES + 3) / 4;       // 4 waves per 256-thread block

    // ---- layer 0 (in=64) + relu
    gemm_kernel<64><<<gemm_grid, 256, 0, stream>>>(x, W[0], bufB, N_NODES);
    al_kernel<<<al_grid, 256, 0, stream>>>(bufB, As[0], Ad[0], alS, alD, N_NODES);
    aggregate_kernel<<<agg_grid, 256, 0, stream>>>(bufB, alS, alD, row_ptr, col_src,
                                                   B[0], bufA, N_NODES, 1);
    // ---- layer 1 (in=128) + relu
    gemm_kernel<128><<<gemm_grid, 256, 0, stream>>>(bufA, W[1], bufB, N_NODES);
    al_kernel<<<al_grid, 256, 0, stream>>>(bufB, As[1], Ad[1], alS, alD, N_NODES);
    aggregate_kernel<<<agg_grid, 256, 0, stream>>>(bufB, alS, alD, row_ptr, col_src,
                                                   B[1], bufA, N_NODES, 1);
    // ---- layer 2 (in=128), no relu
    gemm_kernel<128><<<gemm_grid, 256, 0, stream>>>(bufA, W[2], bufB, N_NODES);
    al_kernel<<<al_grid, 256, 0, stream>>>(bufB, As[2], Ad[2], alS, alD, N_NODES);
    aggregate_kernel<<<agg_grid, 256, 0, stream>>>(bufB, alS, alD, row_ptr, col_src,
                                                   B[2], bufA, N_NODES, 0);

    // ---- global mean pool
    hipMemsetAsync(sums, 0, (size_t)NGRAPH * 128 * 4, stream);
    gstart_kernel<<<2, 256, 0, stream>>>(bat, gstart, N_NODES);
    pool_kernel<<<(N_NODES + 63) / 64, 128, 0, stream>>>(bufA, bat, sums, N_NODES);
    div_kernel<<<(NGRAPH * 128 + 255) / 256, 256, 0, stream>>>(sums, gstart, outp);
}